// Round 3
// baseline (69.798 us; speedup 1.0000x reference)
//
#include <hip/hip_runtime.h>

#define H 4096
#define W 4096
#define R 4              // output rows per block
#define NR (R+2)         // rows loaded (r0-1 .. r0+R)
#define TC 4             // cols per thread
#define TPB 256
#define STRIP (TPB*TC)   // 1024 cols per block
#define NSTRIP (W/STRIP) // 4
#define NBAND (H/R)      // 1024
#define NBLK (NSTRIP*NBAND) // 4096

__global__ __launch_bounds__(TPB, 4)
void wbce_kernel(const float* __restrict__ outp, const float* __restrict__ segp,
                 float* __restrict__ dsum) {
  // XCD-chunk swizzle (bijective: NBLK % 8 == 0): physical p -> logical so each
  // XCD owns a contiguous run of row-bands (adjacent bands share 2 halo rows in L2).
  const int p = blockIdx.x;
  const int logical = (p & 7) * (NBLK / 8) + (p >> 3);
  const int strip = logical & (NSTRIP - 1);
  const int band  = logical >> 2;            // NSTRIP == 4
  const int t  = threadIdx.x;
  const int c0 = strip * STRIP + t * TC;
  const int r0 = band * R;
  const bool lv = (c0 > 0);
  const bool rv = (c0 + TC < W);

  float s[NR][TC], o[NR][TC];
  float sl[NR], sr[NR], ol[NR], orr[NR];

  const float* __restrict__ sp = segp + (size_t)r0 * W + c0;  // row r0, this thread's cols
  const float* __restrict__ op = outp + (size_t)r0 * W + c0;

  if (band > 0 && band < NBAND - 1) {
    // interior fast path: all NR rows valid, no per-row predication.
    // Issue ALL loads up front -> max memory-level parallelism.
    #pragma unroll
    for (int i = 0; i < NR; ++i) {
      const long off = (long)(i - 1) * W;
      const float4 fs = *reinterpret_cast<const float4*>(sp + off);
      const float4 fo = *reinterpret_cast<const float4*>(op + off);
      s[i][0] = fs.x; s[i][1] = fs.y; s[i][2] = fs.z; s[i][3] = fs.w;
      o[i][0] = fo.x; o[i][1] = fo.y; o[i][2] = fo.z; o[i][3] = fo.w;
    }
    #pragma unroll
    for (int i = 0; i < NR; ++i) {
      const long off = (long)(i - 1) * W;
      sl[i]  = lv ? sp[off - 1]  : 0.f;   // L1 hits (same lines as neighbors' float4s)
      ol[i]  = lv ? op[off - 1]  : 0.f;
      sr[i]  = rv ? sp[off + TC] : 0.f;
      orr[i] = rv ? op[off + TC] : 0.f;
    }
  } else {
    #pragma unroll
    for (int i = 0; i < NR; ++i) {
      const int ri = r0 - 1 + i;
      const bool v = (ri >= 0) && (ri < H);
      const long off = (long)(i - 1) * W;
      if (v) {
        const float4 fs = *reinterpret_cast<const float4*>(sp + off);
        const float4 fo = *reinterpret_cast<const float4*>(op + off);
        s[i][0] = fs.x; s[i][1] = fs.y; s[i][2] = fs.z; s[i][3] = fs.w;
        o[i][0] = fo.x; o[i][1] = fo.y; o[i][2] = fo.z; o[i][3] = fo.w;
        sl[i]  = lv ? sp[off - 1]  : 0.f;
        ol[i]  = lv ? op[off - 1]  : 0.f;
        sr[i]  = rv ? sp[off + TC] : 0.f;
        orr[i] = rv ? op[off + TC] : 0.f;
      } else {
        #pragma unroll
        for (int k = 0; k < TC; ++k) { s[i][k] = 0.f; o[i][k] = 0.f; }
        sl[i] = sr[i] = ol[i] = orr[i] = 0.f;
      }
    }
  }

  float acc = 0.f;
  #pragma unroll
  for (int i = 0; i < R; ++i) {          // output row r0+i; window rows i..i+2
    float cs[TC], co[TC];
    #pragma unroll
    for (int k = 0; k < TC; ++k) {
      cs[k] = s[i][k] + s[i+1][k] + s[i+2][k];
      co[k] = o[i][k] + o[i+1][k] + o[i+2][k];
    }
    const float csL = sl[i] + sl[i+1] + sl[i+2];
    const float csR = sr[i] + sr[i+1] + sr[i+2];
    const float coL = ol[i] + ol[i+1] + ol[i+2];
    const float coR = orr[i] + orr[i+1] + orr[i+2];

    #pragma unroll
    for (int k = 0; k < TC; ++k) {
      const float cl  = (k == 0)    ? csL : cs[k-1];
      const float cr  = (k == TC-1) ? csR : cs[k+1];
      const float nsS = cl + cs[k] + cr - s[i+1][k];   // 8-neighbor sum of seg
      const float col = (k == 0)    ? coL : co[k-1];
      const float cor = (k == TC-1) ? coR : co[k+1];
      const float nsO = col + co[k] + cor - o[i+1][k]; // 8-neighbor sum of out
      const float w1 = 9.f - nsS;                      // sig_seg_1
      const float m0 = 1.f + nsO;                      // sig_out_0
      const float sv = s[i+1][k], ov = o[i+1][k];
      acc += w1 * sv * __logf(ov + 1e-5f) + m0 * (1.f - sv) * __logf(1.f - ov + 1e-5f);
    }
  }

  // wave reduce (64 lanes)
  #pragma unroll
  for (int off = 32; off > 0; off >>= 1) acc += __shfl_down(acc, off, 64);

  __shared__ float wsum[TPB / 64];
  if ((t & 63) == 0) wsum[t >> 6] = acc;
  __syncthreads();
  if (t == 0) {
    const float ssum = wsum[0] + wsum[1] + wsum[2] + wsum[3];
    atomicAdd(dsum, ssum * (-1.0f / ((float)H * (float)W)));  // loss = -mean
  }
}

extern "C" void kernel_launch(void* const* d_in, const int* in_sizes, int n_in,
                              void* d_out, int out_size, void* d_ws, size_t ws_size,
                              hipStream_t stream) {
  const float* outp = (const float*)d_in[0];  // out_image
  const float* segp = (const float*)d_in[1];  // segment_image
  float* o = (float*)d_out;
  hipMemsetAsync(o, 0, sizeof(float), stream);   // graph-capturable; re-zero every call
  wbce_kernel<<<dim3(NBLK), TPB, 0, stream>>>(outp, segp, o);
}